// Round 10
// baseline (856.626 us; speedup 1.0000x reference)
//
#include <hip/hip_runtime.h>
#include <hip/hip_bf16.h>

#define Hd 128
#define Nn 512
#define LSTRIDE 136  // bf16 per LDS tile row (128 + 8 pad; 272 B keeps b128/b64 align)

typedef __bf16 bf16x8 __attribute__((ext_vector_type(8)));
typedef __bf16 bf16x4 __attribute__((ext_vector_type(4)));
typedef float  floatx4 __attribute__((ext_vector_type(4)));

__device__ __forceinline__ float frcp(float x){ return __builtin_amdgcn_rcpf(x); }
__device__ __forceinline__ float fsilu(float x){ return x * frcp(1.f + __expf(-x)); }
__device__ __forceinline__ float fsigm(float x){ return frcp(1.f + __expf(-x)); }
__device__ __forceinline__ float ftanh(float x){ return 1.f - 2.f * frcp(__expf(2.f*x) + 1.f); }
__device__ __forceinline__ float rfl(float x){
  return __int_as_float(__builtin_amdgcn_readfirstlane(__float_as_int(x)));
}

// ---------------------------------------------------------------------------
// prep: blocks 0..255   -> A/Bm (4 rows each, 256 thr, split-c, 8 acc ILP)
//       blocks 256..279 -> weight swizzle (coalesced loads, scattered stores)
//       blocks 280..287 -> zero magg/posu/velu (137216 words)
// A[row] = h[row]@We1[0:128]+be1 ; Bm[row] = h[row]@We1[128:256]
// swizzle fragment order: frag[tile][s][lane][j] = W[32s+(lane>>4)*8+j][16*tile+(lane&15)]
// ---------------------------------------------------------------------------
__global__ __launch_bounds__(256) void prep(const float* __restrict__ h,
                                            const float* __restrict__ We1,
                                            const float* __restrict__ be1,
                                            const float* __restrict__ We2,
                                            const float* __restrict__ Wp1,
                                            const float* __restrict__ Wv1,
                                            float* __restrict__ A,
                                            float* __restrict__ Bm,
                                            __bf16* __restrict__ dst,
                                            float* __restrict__ zbase){
  if (blockIdx.x < 256){
    const int r0 = blockIdx.x * 4;
    const int k = threadIdx.x & 127, ch = threadIdx.x >> 7;
    __shared__ float hL[4][Hd];
    __shared__ float pa[2][4][Hd], pb[2][4][Hd];
    for (int idx = threadIdx.x; idx < 4*Hd; idx += 256)
      hL[idx >> 7][idx & 127] = h[r0*Hd + idx];
    __syncthreads();
    float a[4] = {0.f,0.f,0.f,0.f}, bb[4] = {0.f,0.f,0.f,0.f};
    const int cbase = ch*64;
    #pragma unroll 4
    for (int cc = 0; cc < 64; ++cc){
      const int c = cbase + cc;
      const float wa = We1[c*Hd + k];
      const float wb = We1[(c + Hd)*Hd + k];
      #pragma unroll
      for (int rr = 0; rr < 4; ++rr){
        a[rr]  += hL[rr][c] * wa;
        bb[rr] += hL[rr][c] * wb;
      }
    }
    #pragma unroll
    for (int rr = 0; rr < 4; ++rr){ pa[ch][rr][k] = a[rr]; pb[ch][rr][k] = bb[rr]; }
    __syncthreads();
    if (threadIdx.x < Hd){
      const float be = be1[k];
      #pragma unroll
      for (int rr = 0; rr < 4; ++rr){
        A[(r0+rr)*Hd + k]  = pa[0][rr][k] + pa[1][rr][k] + be;
        Bm[(r0+rr)*Hd + k] = pb[0][rr][k] + pb[1][rr][k];
      }
    }
  } else if (blockIdx.x < 280){
    const int blk = blockIdx.x - 256;         // 0..23, 8 per matrix
    const int which = blk >> 3, m = blk & 7;  // m: 1/8 of one matrix
    const float* src = (which == 0) ? We2 : (which == 1 ? Wp1 : Wv1);
    __bf16* d = dst + which * (Hd*Hd);
    #pragma unroll
    for (int it = 0; it < 8; ++it){
      const int sidx = m*2048 + it*256 + threadIdx.x;   // source-linear: coalesced load
      const int kk = sidx >> 7, cc = sidx & 127;
      const int s = kk >> 5, j = kk & 7;
      const int lane = ((kk >> 3) & 3)*16 + (cc & 15);
      const int n = cc >> 4;
      d[n*2048 + s*512 + lane*8 + j] = (__bf16)src[sidx];
    }
  } else {
    const int t0 = (blockIdx.x - 280)*256 + threadIdx.x;
    for (int idx = t0; idx < 137216; idx += 2048) zbase[idx] = 0.f;
  }
}

// ---------------------------------------------------------------------------
// Wave-local GEMM: acc[fm][n] = W^T x m^T over k=128.  A = W frags (global,
// pre-swizzled), B = wave-private bufij rows (LDS b128).  D: col=j=16n+l15,
// row = feat = 16*fm + 4*q + r.
// ---------------------------------------------------------------------------
__device__ __forceinline__ void gemm_w(const bf16x8* __restrict__ Ws,
                                       const __bf16* __restrict__ myBuf,
                                       int lane, int q, int l15,
                                       floatx4 acc[8][2]){
  const floatx4 fzero = {0.f,0.f,0.f,0.f};
  #pragma unroll
  for (int fm = 0; fm < 8; ++fm){ acc[fm][0] = fzero; acc[fm][1] = fzero; }
  #pragma unroll
  for (int s = 0; s < 4; ++s){
    const int fo = s*32 + q*8;
    const bf16x8 b0 = *(const bf16x8*)&myBuf[l15*LSTRIDE + fo];
    const bf16x8 b1 = *(const bf16x8*)&myBuf[(16 + l15)*LSTRIDE + fo];
    #pragma unroll
    for (int fm = 0; fm < 8; ++fm){
      const bf16x8 a = Ws[(fm*4 + s)*64 + lane];
      acc[fm][0] = __builtin_amdgcn_mfma_f32_16x16x32_bf16(a, b0, acc[fm][0], 0, 0, 0);
      acc[fm][1] = __builtin_amdgcn_mfma_f32_16x16x32_bf16(a, b1, acc[fm][1], 0, 0, 0);
    }
  }
}

// head dot: per-j 128-feat dot of silu(att*acc+bias)*w2, wave-local reduce.
__device__ __forceinline__ float2 head_dot(floatx4 acc[8][2], float att0, float att1,
                                           const float* __restrict__ biasL,
                                           const float* __restrict__ w2L, int q){
  float p0 = 0.f, p1 = 0.f;
  #pragma unroll
  for (int fm = 0; fm < 8; ++fm){
    const int fb = fm*16 + q*4;
    const floatx4 bb = *(const floatx4*)&biasL[fb];
    const floatx4 w2 = *(const floatx4*)&w2L[fb];
    #pragma unroll
    for (int r = 0; r < 4; ++r){
      p0 += fsilu(fmaf(att0, acc[fm][0][r], bb[r])) * w2[r];
      p1 += fsilu(fmaf(att1, acc[fm][1][r], bb[r])) * w2[r];
    }
  }
  p0 += __shfl_xor(p0, 16, 64); p0 += __shfl_xor(p0, 32, 64);
  p1 += __shfl_xor(p1, 16, 64); p1 += __shfl_xor(p1, 32, 64);
  return make_float2(p0, p1);
}

// ---------------------------------------------------------------------------
// main: 2 blocks per (b,i); wave w owns j-range [w*32, w*32+32) of each
// 128-j tile — ZERO in-loop barriers (all state wave-local).
// ---------------------------------------------------------------------------
__global__ __launch_bounds__(256) void egnn_main(
    const float* __restrict__ pos, const float* __restrict__ vel,
    const float* __restrict__ We1, const float* __restrict__ be2,
    const float* __restrict__ Wa,  const float* __restrict__ ba,
    const float* __restrict__ bp1, const float* __restrict__ Wp2,
    const float* __restrict__ bv1, const float* __restrict__ Wv2,
    const float* __restrict__ A,   const float* __restrict__ Bm,
    const __bf16* __restrict__ Wsw,
    float* __restrict__ magg, float* __restrict__ posu, float* __restrict__ velu){

  const int t    = threadIdx.x;
  const int w    = t >> 6;
  const int lane = t & 63;
  const int q    = lane >> 4;
  const int l15  = lane & 15;
  const int node = blockIdx.x >> 1;     // (b*512 + i)
  const int half = blockIdx.x & 1;
  const int b    = node >> 9;

  __shared__ float AiL[Hd], wpL[Hd], wvL[Hd];
  __shared__ float be2L[Hd], bp1L[Hd], bv1L[Hd], WaL[Hd], Wp2L[Hd], Wv2L[Hd];
  __shared__ __align__(16) __bf16 bufij[4*32*LSTRIDE];   // 4 wave-private slices
  __shared__ float attL[128];                            // 4 wave-private slices

  if (t < Hd){
    AiL[t]  = A[node*Hd + t];
    wpL[t]  = We1[256*Hd + t];
    wvL[t]  = We1[257*Hd + t];
    be2L[t] = be2[t]; bp1L[t] = bp1[t]; bv1L[t] = bv1[t];
    WaL[t]  = Wa[t];  Wp2L[t] = Wp2[t]; Wv2L[t] = Wv2[t];
  }
  const float baV = ba[0];
  const float* pi = &pos[(size_t)node*3];
  const float* vi = &vel[(size_t)node*3];
  const float px = rfl(pi[0]), py = rfl(pi[1]), pz = rfl(pi[2]);
  const float ux = rfl(vi[0]), uy = rfl(vi[1]), uz = rfl(vi[2]);
  __syncthreads();   // the only barrier

  const bf16x8* We2s = (const bf16x8*)(Wsw);
  const bf16x8* Wp1s = (const bf16x8*)(Wsw + Hd*Hd);
  const bf16x8* Wv1s = (const bf16x8*)(Wsw + 2*Hd*Hd);
  __bf16* myBuf = &bufij[w*32*LSTRIDE];
  float*  myAtt = &attL[w*32];

  float accP0=0.f, accP1=0.f, accP2=0.f, accV0=0.f, accV1=0.f, accV2=0.f;
  float acc8[8];
  #pragma unroll
  for (int e = 0; e < 8; ++e) acc8[e] = 0.f;

  for (int jt = 0; jt < 2; ++jt){
    const int jb = half*(Nn/2) + jt*128 + w*32;
    const size_t row0 = (size_t)(b*Nn + jb + l15);
    const size_t row1 = row0 + 16;

    // distances for this lane's two j's
    float dp[2], dv[2];
    {
      const float* pj0 = &pos[row0*3]; const float* vj0 = &vel[row0*3];
      const float* pj1 = &pos[row1*3]; const float* vj1 = &vel[row1*3];
      float dx = px - pj0[0], dy = py - pj0[1], dz = pz - pj0[2];
      dp[0] = dx*dx + dy*dy + dz*dz;
      dx = px - pj1[0]; dy = py - pj1[1]; dz = pz - pj1[2];
      dp[1] = dx*dx + dy*dy + dz*dz;
      float ex = ux - vj0[0], ey = uy - vj0[1], ez = uz - vj0[2];
      dv[0] = ex*ex + ey*ey + ez*ez;
      ex = ux - vj1[0]; ey = uy - vj1[1]; ez = uz - vj1[2];
      dv[1] = ex*ex + ey*ey + ez*ez;
    }

    floatx4 acc[8][2];
    const floatx4 fzero = {0.f,0.f,0.f,0.f};
    #pragma unroll
    for (int fm = 0; fm < 8; ++fm){ acc[fm][0] = fzero; acc[fm][1] = fzero; }

    // ---- GEMM1 with register-built B-fragments (edge MLP layer 1 fused) ---
    #pragma unroll
    for (int s = 0; s < 4; ++s){
      const int fo = s*32 + q*8;
      const floatx4 A0 = *(const floatx4*)&AiL[fo], A1 = *(const floatx4*)&AiL[fo+4];
      const floatx4 P0 = *(const floatx4*)&wpL[fo], P1 = *(const floatx4*)&wpL[fo+4];
      const floatx4 V0 = *(const floatx4*)&wvL[fo], V1 = *(const floatx4*)&wvL[fo+4];
      bf16x8 mf[2];
      #pragma unroll
      for (int n = 0; n < 2; ++n){
        const floatx4* Bp = (const floatx4*)&Bm[(n ? row1 : row0)*Hd + fo];
        const floatx4 b0 = Bp[0], b1 = Bp[1];
        float x[8];
        #pragma unroll
        for (int e = 0; e < 4; ++e){
          x[e]   = fsilu(A0[e] + b0[e] + dp[n]*P0[e] + dv[n]*V0[e]);
          x[4+e] = fsilu(A1[e] + b1[e] + dp[n]*P1[e] + dv[n]*V1[e]);
        }
        union { bf16x8 v; __hip_bfloat162 h2[4]; } o;
        o.h2[0] = __float22bfloat162_rn(make_float2(x[0], x[1]));
        o.h2[1] = __float22bfloat162_rn(make_float2(x[2], x[3]));
        o.h2[2] = __float22bfloat162_rn(make_float2(x[4], x[5]));
        o.h2[3] = __float22bfloat162_rn(make_float2(x[6], x[7]));
        mf[n] = o.v;
      }
      #pragma unroll
      for (int fm = 0; fm < 8; ++fm){
        const bf16x8 a = We2s[(fm*4 + s)*64 + lane];
        acc[fm][0] = __builtin_amdgcn_mfma_f32_16x16x32_bf16(a, mf[0], acc[fm][0], 0, 0, 0);
        acc[fm][1] = __builtin_amdgcn_mfma_f32_16x16x32_bf16(a, mf[1], acc[fm][1], 0, 0, 0);
      }
    }

    // ---- epilogue 1: silu -> wave-private bufij; Wa dot -> att ------------
    float aw0 = 0.f, aw1 = 0.f;
    #pragma unroll
    for (int fm = 0; fm < 8; ++fm){
      const int fb = fm*16 + q*4;
      const floatx4 be = *(const floatx4*)&be2L[fb];
      const floatx4 wa = *(const floatx4*)&WaL[fb];
      float s0[4], s1[4];
      #pragma unroll
      for (int r = 0; r < 4; ++r){
        s0[r] = fsilu(acc[fm][0][r] + be[r]);
        s1[r] = fsilu(acc[fm][1][r] + be[r]);
        aw0 += s0[r]*wa[r];
        aw1 += s1[r]*wa[r];
      }
      union { bf16x4 v; __hip_bfloat162 h2[2]; } k0, k1;
      k0.h2[0] = __float22bfloat162_rn(make_float2(s0[0], s0[1]));
      k0.h2[1] = __float22bfloat162_rn(make_float2(s0[2], s0[3]));
      k1.h2[0] = __float22bfloat162_rn(make_float2(s1[0], s1[1]));
      k1.h2[1] = __float22bfloat162_rn(make_float2(s1[2], s1[3]));
      *(bf16x4*)&myBuf[l15*LSTRIDE + fb]        = k0.v;
      *(bf16x4*)&myBuf[(16 + l15)*LSTRIDE + fb] = k1.v;
    }
    aw0 += __shfl_xor(aw0, 16, 64); aw0 += __shfl_xor(aw0, 32, 64);
    aw1 += __shfl_xor(aw1, 16, 64); aw1 += __shfl_xor(aw1, 32, 64);
    const float att0 = fsigm(aw0 + baV);
    const float att1 = fsigm(aw1 + baV);
    if (lane < 16){ myAtt[l15] = att0; myAtt[16 + l15] = att1; }

    // ---- GEMM2 (pos head) -------------------------------------------------
    gemm_w(Wp1s, myBuf, lane, q, l15, acc);
    {
      const float2 pp = head_dot(acc, att0, att1, bp1L, Wp2L, q);
      const float pw0 = ftanh(pp.x), pw1 = ftanh(pp.y);
      const float* pj0 = &pos[row0*3];
      const float* pj1 = &pos[row1*3];
      accP0 += (px - pj0[0])*pw0 + (px - pj1[0])*pw1;
      accP1 += (py - pj0[1])*pw0 + (py - pj1[1])*pw1;
      accP2 += (pz - pj0[2])*pw0 + (pz - pj1[2])*pw1;
    }

    // ---- GEMM3 (vel head) -------------------------------------------------
    gemm_w(Wv1s, myBuf, lane, q, l15, acc);
    {
      const float2 vv = head_dot(acc, att0, att1, bv1L, Wv2L, q);
      const float vw0 = ftanh(vv.x), vw1 = ftanh(vv.y);
      const float* vj0 = &vel[row0*3];
      const float* vj1 = &vel[row1*3];
      accV0 += (ux - vj0[0])*vw0 + (ux - vj1[0])*vw1;
      accV1 += (uy - vj0[1])*vw0 + (uy - vj1[1])*vw1;
      accV2 += (uz - vj0[2])*vw0 + (uz - vj1[2])*vw1;
    }

    // ---- m_agg: wave-local scan of att_j * m[j][feat] ---------------------
    {
      const int fg = lane & 15, jr = lane >> 4;
      #pragma unroll
      for (int k = 0; k < 8; ++k){
        const int jl = jr + 4*k;
        const float aj = myAtt[jl];
        const bf16x8 v = *(const bf16x8*)&myBuf[jl*LSTRIDE + fg*8];
        #pragma unroll
        for (int e = 0; e < 8; ++e) acc8[e] += aj * (float)v[e];
      }
    }
  }

  // -------- end-of-kernel reductions + atomics -----------------------------
  // pos/vel: each j counted once per q-group (x4) -> scale 0.25
  float r6[6] = {accP0, accP1, accP2, accV0, accV1, accV2};
  #pragma unroll
  for (int off = 1; off < 64; off <<= 1){
    #pragma unroll
    for (int e = 0; e < 6; ++e) r6[e] += __shfl_xor(r6[e], off, 64);
  }
  if (lane == 0){
    atomicAdd(&posu[node*3+0], r6[0]*0.25f);
    atomicAdd(&posu[node*3+1], r6[1]*0.25f);
    atomicAdd(&posu[node*3+2], r6[2]*0.25f);
    atomicAdd(&velu[node*3+0], r6[3]*0.25f);
    atomicAdd(&velu[node*3+1], r6[4]*0.25f);
    atomicAdd(&velu[node*3+2], r6[5]*0.25f);
  }
  // m_agg: combine jr-groups (lanes differing in bits 4/5), lanes<16 commit
  #pragma unroll
  for (int e = 0; e < 8; ++e){
    acc8[e] += __shfl_xor(acc8[e], 16, 64);
    acc8[e] += __shfl_xor(acc8[e], 32, 64);
  }
  if (lane < 16){
    #pragma unroll
    for (int e = 0; e < 8; ++e)
      atomicAdd(&magg[node*Hd + lane*8 + e], acc8[e]);
  }
}

// ---------------------------------------------------------------------------
// final: node MLP (fp32) + residual + pos/vel clamp; 1 row/block, split-k
// ---------------------------------------------------------------------------
__global__ __launch_bounds__(256) void egnn_final(
    const float* __restrict__ h, const float* __restrict__ pos, const float* __restrict__ vel,
    const float* __restrict__ Wn1, const float* __restrict__ bn1,
    const float* __restrict__ Wn2, const float* __restrict__ bn2,
    const float* __restrict__ magg, const float* __restrict__ posu,
    const float* __restrict__ velu, float* __restrict__ out){
  const int row = blockIdx.x;
  const int t = threadIdx.x;
  const int k = t & 127, ch = t >> 7;
  __shared__ float ni[2*Hd];     // [0..127]=h, [128..255]=magg
  __shared__ float p1[2][Hd], t1[Hd];
  ni[t] = (t < Hd) ? h[row*Hd + t] : magg[row*Hd + (t - Hd)];
  __syncthreads();
  {
    float a0=0.f,a1=0.f,a2=0.f,a3=0.f;
    const int cb = ch*Hd;
    #pragma unroll 8
    for (int cc = 0; cc < Hd; cc += 4){
      a0 += ni[cb+cc+0] * Wn1[(cb+cc+0)*Hd + k];
      a1 += ni[cb+cc+1] * Wn1[(cb+cc+1)*Hd + k];
      a2 += ni[cb+cc+2] * Wn1[(cb+cc+2)*Hd + k];
      a3 += ni[cb+cc+3] * Wn1[(cb+cc+3)*Hd + k];
    }
    p1[ch][k] = (a0+a1)+(a2+a3);
  }
  __syncthreads();
  if (t < Hd) t1[t] = fsilu(p1[0][t] + p1[1][t] + bn1[t]);
  __syncthreads();
  {
    float a0=0.f,a1=0.f,a2=0.f,a3=0.f;
    const int cb = ch*64;
    #pragma unroll 8
    for (int cc = 0; cc < 64; cc += 4){
      a0 += t1[cb+cc+0] * Wn2[(cb+cc+0)*Hd + k];
      a1 += t1[cb+cc+1] * Wn2[(cb+cc+1)*Hd + k];
      a2 += t1[cb+cc+2] * Wn2[(cb+cc+2)*Hd + k];
      a3 += t1[cb+cc+3] * Wn2[(cb+cc+3)*Hd + k];
    }
    p1[ch][k] = (a0+a1)+(a2+a3);
  }
  __syncthreads();
  if (t < Hd){
    out[row*Hd + t] = ni[t] + p1[0][t] + p1[1][t] + bn2[t];
  } else if (t < Hd + 3){
    const int d = t - Hd;
    const float v = pos[row*3 + d] + posu[row*3 + d] * (1.f/511.f);
    out[2*Nn*Hd + row*3 + d] = fminf(fmaxf(v, -100.f), 100.f);
  } else if (t < Hd + 6){
    const int d = t - Hd - 3;
    const float v = vel[row*3 + d] + velu[row*3 + d] * (1.f/511.f);
    out[2*Nn*Hd + 2*Nn*3 + row*3 + d] = fminf(fmaxf(v, -100.f), 100.f);
  }
}

// ---------------------------------------------------------------------------
extern "C" void kernel_launch(void* const* d_in, const int* in_sizes, int n_in,
                              void* d_out, int out_size, void* d_ws, size_t ws_size,
                              hipStream_t stream){
  const float* h   = (const float*)d_in[0];
  const float* pos = (const float*)d_in[1];
  const float* vel = (const float*)d_in[2];
  const float* We1 = (const float*)d_in[3];
  const float* be1 = (const float*)d_in[4];
  const float* We2 = (const float*)d_in[5];
  const float* be2 = (const float*)d_in[6];
  const float* Wa  = (const float*)d_in[7];
  const float* ba  = (const float*)d_in[8];
  const float* Wp1 = (const float*)d_in[9];
  const float* bp1 = (const float*)d_in[10];
  const float* Wp2 = (const float*)d_in[11];
  const float* Wv1 = (const float*)d_in[12];
  const float* bv1 = (const float*)d_in[13];
  const float* Wv2 = (const float*)d_in[14];
  const float* Wn1 = (const float*)d_in[15];
  const float* bn1 = (const float*)d_in[16];
  const float* Wn2 = (const float*)d_in[17];
  const float* bn2 = (const float*)d_in[18];

  float* ws = (float*)d_ws;
  float*  A    = ws;                     // 1024*128 floats
  float*  Bmm  = ws + 131072;            // 1024*128
  float*  magg = ws + 262144;            // 1024*128  (zeroed by prep)
  float*  posu = ws + 393216;            // 1024*3    (zeroed by prep)
  float*  velu = ws + 396288;            // 1024*3    (zeroed by prep)
  __bf16* Wsw  = (__bf16*)(ws + 399360); // 3*16384 bf16

  prep      <<<dim3(288),  dim3(256), 0, stream>>>(h, We1, be1, We2, Wp1, Wv1,
                                                   A, Bmm, Wsw, magg);
  egnn_main <<<dim3(2048), dim3(256), 0, stream>>>(pos, vel, We1, be2, Wa, ba, bp1, Wp2,
                                                   bv1, Wv2, A, Bmm, Wsw, magg, posu, velu);
  egnn_final<<<dim3(1024), dim3(256), 0, stream>>>(h, pos, vel, Wn1, bn1, Wn2, bn2,
                                                   magg, posu, velu, (float*)d_out);
}

// Round 11
// 232.093 us; speedup vs baseline: 3.6909x; 3.6909x over previous
//
#include <hip/hip_runtime.h>
#include <hip/hip_bf16.h>
#include <hip/hip_cooperative_groups.h>

namespace cg = cooperative_groups;

#define Hd 128
#define Nn 512
#define TJ 32
#define LSTRIDE 136  // bf16 per LDS tile row (128 + 8 pad; 272 B keeps b128/b64 align)

typedef __bf16 bf16x8 __attribute__((ext_vector_type(8)));
typedef __bf16 bf16x4 __attribute__((ext_vector_type(4)));
typedef float  floatx4 __attribute__((ext_vector_type(4)));

__device__ __forceinline__ float frcp(float x){ return __builtin_amdgcn_rcpf(x); }
__device__ __forceinline__ float fsilu(float x){ return x * frcp(1.f + __expf(-x)); }
__device__ __forceinline__ float fsigm(float x){ return frcp(1.f + __expf(-x)); }
__device__ __forceinline__ float ftanh(float x){ return 1.f - 2.f * frcp(__expf(2.f*x) + 1.f); }
__device__ __forceinline__ float rfl(float x){
  return __int_as_float(__builtin_amdgcn_readfirstlane(__float_as_int(x)));
}

// ===========================================================================
// Shared device helpers (R9-proven)
// ===========================================================================
// Transposed K-loop: D = W^T x m^T. A-operand = pre-swizzled W (global),
// B-operand = m rows from LDS ([j][feat] layout, b128 reads).
__device__ __forceinline__ void gemm_kloopT(const __bf16* __restrict__ buf,
                                            const bf16x8* __restrict__ Ws,
                                            int w, int lane, int q, int l15,
                                            floatx4 acc[2][2]){
  const floatx4 zero = {0.f, 0.f, 0.f, 0.f};
  #pragma unroll
  for (int m = 0; m < 2; ++m){ acc[m][0] = zero; acc[m][1] = zero; }
  #pragma unroll
  for (int s = 0; s < 4; ++s){
    bf16x8 bf[2];
    #pragma unroll
    for (int n = 0; n < 2; ++n)
      bf[n] = *(const bf16x8*)&buf[(16*n + l15)*LSTRIDE + s*32 + q*8];
    const bf16x8 a0 = Ws[((2*w + 0)*4 + s)*64 + lane];
    const bf16x8 a1 = Ws[((2*w + 1)*4 + s)*64 + lane];
    #pragma unroll
    for (int n = 0; n < 2; ++n){
      acc[0][n] = __builtin_amdgcn_mfma_f32_16x16x32_bf16(a0, bf[n], acc[0][n], 0, 0, 0);
      acc[1][n] = __builtin_amdgcn_mfma_f32_16x16x32_bf16(a1, bf[n], acc[1][n], 0, 0, 0);
    }
  }
}

// head epilogue: per-j dot over this wave's 32 feats of silu(att*acc+b)*w2,
// reduced in-register (r,m) then across q-groups (xor16/xor32) -> part[w][j]
__device__ __forceinline__ void wdotT(floatx4 acc[2][2], float att0, float att1,
                                      const float* __restrict__ biasL,
                                      const float* __restrict__ w2L,
                                      int w, int lane, int q, int l15,
                                      float (*part)[TJ]){
  const int fb0 = 32*w + 4*q, fb1 = fb0 + 16;
  const floatx4 bb0 = *(const floatx4*)&biasL[fb0];
  const floatx4 bb1 = *(const floatx4*)&biasL[fb1];
  const floatx4 w0  = *(const floatx4*)&w2L[fb0];
  const floatx4 w1  = *(const floatx4*)&w2L[fb1];
  float p0 = 0.f, p1 = 0.f;
  #pragma unroll
  for (int r = 0; r < 4; ++r){
    p0 += fsilu(fmaf(att0, acc[0][0][r], bb0[r])) * w0[r];
    p0 += fsilu(fmaf(att0, acc[1][0][r], bb1[r])) * w1[r];
    p1 += fsilu(fmaf(att1, acc[0][1][r], bb0[r])) * w0[r];
    p1 += fsilu(fmaf(att1, acc[1][1][r], bb1[r])) * w1[r];
  }
  p0 += __shfl_xor(p0, 16, 64); p0 += __shfl_xor(p0, 32, 64);
  p1 += __shfl_xor(p1, 16, 64); p1 += __shfl_xor(p1, 32, 64);
  if (lane < 16){
    part[w][l15]      = p0;
    part[w][16 + l15] = p1;
  }
}

// ===========================================================================
// COOPERATIVE single kernel: block = node. Phase0 (A->LDS, Bm->global,
// weight swizzle by blocks 0..23) -> grid.sync -> R9 tile loop (16 tiles of
// 32 j, 3 barriers/tile) -> in-block fused tail (node MLP + clamped writes).
// ===========================================================================
__global__ __launch_bounds__(256) void egnn_coop(
    const float* __restrict__ h,
    const float* __restrict__ pos, const float* __restrict__ vel,
    const float* __restrict__ We1, const float* __restrict__ be1,
    const float* __restrict__ be2,
    const float* __restrict__ Wa,  const float* __restrict__ ba,
    const float* __restrict__ bp1, const float* __restrict__ Wp2,
    const float* __restrict__ bv1, const float* __restrict__ Wv2,
    const float* __restrict__ Wn1, const float* __restrict__ bn1,
    const float* __restrict__ Wn2, const float* __restrict__ bn2,
    const float* __restrict__ We2, const float* __restrict__ Wp1,
    const float* __restrict__ Wv1,
    float* __restrict__ Bm, __bf16* __restrict__ Wsw,
    float* __restrict__ out){

  const int t    = threadIdx.x;
  const int w    = t >> 6;
  const int lane = t & 63;
  const int q    = lane >> 4;
  const int l15  = lane & 15;
  const int node = blockIdx.x;
  const int b    = node >> 9;

  __shared__ float AiL[Hd], wpL[Hd], wvL[Hd];
  __shared__ float be2L[Hd], bp1L[Hd], bv1L[Hd], WaL[Hd], Wp2L[Hd], Wv2L[Hd];
  __shared__ __align__(16) __bf16 bufm [TJ*LSTRIDE];
  __shared__ __align__(16) __bf16 bufij[TJ*LSTRIDE];
  __shared__ float partAtt[4][TJ], partP[4][TJ], partV[4][TJ];
  __shared__ float attL[TJ];

  // ---------- phase 0: A (self row -> AiL), Bm row, weight swizzle ---------
  {
    const int k = t & 127, ch = t >> 7;
    if (t < Hd) AiL[t] = h[(size_t)node*Hd + t];   // AiL as h-row scratch
    __syncthreads();
    float a = 0.f, bm = 0.f;
    const int cb = ch*64;
    #pragma unroll 4
    for (int cc = 0; cc < 64; ++cc){
      const int c = cb + cc;
      const float hv = AiL[c];
      a  += hv * We1[c*Hd + k];
      bm += hv * We1[(c + Hd)*Hd + k];
    }
    float* pa = (float*)bufm;       // [2][128] scratch
    float* pb = pa + 256;           // [2][128]
    pa[ch*128 + k] = a;
    pb[ch*128 + k] = bm;
    __syncthreads();
    if (t < Hd){
      const float av = pa[t] + pa[128 + t] + be1[t];
      Bm[(size_t)node*Hd + t] = pb[t] + pb[128 + t];
      AiL[t] = av;                  // A row kept in LDS only (self-consumed)
    }
    if (node < 24){
      const int which = node >> 3, m = node & 7;
      const float* src = (which == 0) ? We2 : (which == 1 ? Wp1 : Wv1);
      __bf16* d = Wsw + which * (Hd*Hd);
      #pragma unroll
      for (int it = 0; it < 8; ++it){
        const int sidx = m*2048 + it*256 + t;      // source-linear, coalesced
        const int kk = sidx >> 7, cc2 = sidx & 127;
        const int s = kk >> 5, j = kk & 7;
        const int ln = ((kk >> 3) & 3)*16 + (cc2 & 15);
        const int n = cc2 >> 4;
        d[n*2048 + s*512 + ln*8 + j] = (__bf16)src[sidx];
      }
    }
  }
  cg::this_grid().sync();

  // ---------- init (R9) ----------------------------------------------------
  if (t < Hd){
    wpL[t]  = We1[256*Hd + t];
    wvL[t]  = We1[257*Hd + t];
    be2L[t] = be2[t]; bp1L[t] = bp1[t]; bv1L[t] = bv1[t];
    WaL[t]  = Wa[t];  Wp2L[t] = Wp2[t]; Wv2L[t] = Wv2[t];
  }
  const float baV = ba[0];
  const float* pi = &pos[(size_t)node*3];
  const float* vi = &vel[(size_t)node*3];
  const float px = rfl(pi[0]), py = rfl(pi[1]), pz = rfl(pi[2]);
  const float ux = rfl(vi[0]), uy = rfl(vi[1]), uz = rfl(vi[2]);
  __syncthreads();

  const bf16x8* We2s = (const bf16x8*)(Wsw);
  const bf16x8* Wp1s = (const bf16x8*)(Wsw + Hd*Hd);
  const bf16x8* Wv1s = (const bf16x8*)(Wsw + 2*Hd*Hd);

  float accR[8];
  #pragma unroll
  for (int e = 0; e < 8; ++e) accR[e] = 0.f;

  // ---------- R9 tile loop: 16 tiles of 32 j -------------------------------
  for (int jt = 0; jt < Nn/TJ; ++jt){
    const int j0 = jt * TJ;

    // phase B: edge MLP layer 1 (fp32 -> packed bf16 LDS tile)
    {
      const int g  = t & 15;       // col-group: feats g*8 .. g*8+7
      const int j2 = t >> 4;       // rows j2 and j2+16
      const floatx4 a0 = *(const floatx4*)&AiL[g*8];
      const floatx4 a1 = *(const floatx4*)&AiL[g*8 + 4];
      const floatx4 p0 = *(const floatx4*)&wpL[g*8];
      const floatx4 p1 = *(const floatx4*)&wpL[g*8 + 4];
      const floatx4 v0 = *(const floatx4*)&wvL[g*8];
      const floatx4 v1 = *(const floatx4*)&wvL[g*8 + 4];
      #pragma unroll
      for (int rr = 0; rr < 2; ++rr){
        const int j = j2 + rr*16;
        const int jg = j0 + j;
        const float* pj = &pos[(size_t)(b*Nn + jg)*3];
        const float* vj = &vel[(size_t)(b*Nn + jg)*3];
        const float dx = px - pj[0], dy = py - pj[1], dz = pz - pj[2];
        const float dp = dx*dx + dy*dy + dz*dz;
        const float ex = ux - vj[0], ey = uy - vj[1], ez = uz - vj[2];
        const float dv = ex*ex + ey*ey + ez*ez;
        const floatx4* Bp4 = (const floatx4*)&Bm[((size_t)(b*Nn + jg))*Hd + g*8];
        const floatx4 b0 = Bp4[0], b1 = Bp4[1];
        union { bf16x8 v; __hip_bfloat162 h2[4]; } o;
        float x[8];
        #pragma unroll
        for (int e = 0; e < 4; ++e){
          x[e]   = fsilu(a0[e] + b0[e] + dp*p0[e] + dv*v0[e]);
          x[4+e] = fsilu(a1[e] + b1[e] + dp*p1[e] + dv*v1[e]);
        }
        o.h2[0] = __float22bfloat162_rn(make_float2(x[0], x[1]));
        o.h2[1] = __float22bfloat162_rn(make_float2(x[2], x[3]));
        o.h2[2] = __float22bfloat162_rn(make_float2(x[4], x[5]));
        o.h2[3] = __float22bfloat162_rn(make_float2(x[6], x[7]));
        *(bf16x8*)&bufm[j*LSTRIDE + g*8] = o.v;
      }
    }
    __syncthreads();

    // GEMM1 (transposed): We2^T x m^T -> silu -> bufij; Wa partials
    {
      floatx4 acc[2][2];
      gemm_kloopT(bufm, We2s, w, lane, q, l15, acc);
      const int fb0 = 32*w + 4*q, fb1 = fb0 + 16;
      const floatx4 be0 = *(const floatx4*)&be2L[fb0];
      const floatx4 be1v = *(const floatx4*)&be2L[fb1];
      const floatx4 wa0 = *(const floatx4*)&WaL[fb0];
      const floatx4 wa1 = *(const floatx4*)&WaL[fb1];
      float aw[2];
      #pragma unroll
      for (int n = 0; n < 2; ++n){
        const int j = 16*n + l15;
        float s0[4], s1[4];
        #pragma unroll
        for (int r = 0; r < 4; ++r){
          s0[r] = fsilu(acc[0][n][r] + be0[r]);
          s1[r] = fsilu(acc[1][n][r] + be1v[r]);
        }
        aw[n] = s0[0]*wa0[0] + s0[1]*wa0[1] + s0[2]*wa0[2] + s0[3]*wa0[3]
              + s1[0]*wa1[0] + s1[1]*wa1[1] + s1[2]*wa1[2] + s1[3]*wa1[3];
        union { bf16x4 v; __hip_bfloat162 h2[2]; } p0k, p1k;
        p0k.h2[0] = __float22bfloat162_rn(make_float2(s0[0], s0[1]));
        p0k.h2[1] = __float22bfloat162_rn(make_float2(s0[2], s0[3]));
        p1k.h2[0] = __float22bfloat162_rn(make_float2(s1[0], s1[1]));
        p1k.h2[1] = __float22bfloat162_rn(make_float2(s1[2], s1[3]));
        *(bf16x4*)&bufij[j*LSTRIDE + fb0] = p0k.v;
        *(bf16x4*)&bufij[j*LSTRIDE + fb1] = p1k.v;
      }
      aw[0] += __shfl_xor(aw[0], 16, 64); aw[0] += __shfl_xor(aw[0], 32, 64);
      aw[1] += __shfl_xor(aw[1], 16, 64); aw[1] += __shfl_xor(aw[1], 32, 64);
      if (lane < 16){
        partAtt[w][l15]      = aw[0];
        partAtt[w][16 + l15] = aw[1];
      }
    }
    __syncthreads();

    // GEMM2/3 (transposed) with per-lane attention
    {
      const float att0 = fsigm(partAtt[0][l15] + partAtt[1][l15] +
                               partAtt[2][l15] + partAtt[3][l15] + baV);
      const float att1 = fsigm(partAtt[0][16+l15] + partAtt[1][16+l15] +
                               partAtt[2][16+l15] + partAtt[3][16+l15] + baV);
      if (w == 0 && lane < 16){ attL[l15] = att0; attL[16 + l15] = att1; }
      floatx4 acc[2][2];
      gemm_kloopT(bufij, Wp1s, w, lane, q, l15, acc);
      wdotT(acc, att0, att1, bp1L, Wp2L, w, lane, q, l15, partP);
      gemm_kloopT(bufij, Wv1s, w, lane, q, l15, acc);
      wdotT(acc, att0, att1, bv1L, Wv2L, w, lane, q, l15, partV);
    }
    __syncthreads();

    // step 6: tanh weights + accumulation (register-resident)
    if (w == 0){
      if (lane < TJ){
        const int jg = j0 + lane;
        const float* pj = &pos[(size_t)(b*Nn + jg)*3];
        const float s4 = partP[0][lane] + partP[1][lane] + partP[2][lane] + partP[3][lane];
        const float pw = ftanh(s4);
        accR[0] += (px - pj[0]) * pw;
        accR[1] += (py - pj[1]) * pw;
        accR[2] += (pz - pj[2]) * pw;
      }
    } else if (w == 1){
      if (lane < TJ){
        const int jg = j0 + lane;
        const float* vj = &vel[(size_t)(b*Nn + jg)*3];
        const float s4 = partV[0][lane] + partV[1][lane] + partV[2][lane] + partV[3][lane];
        const float vw = ftanh(s4);
        accR[0] += (ux - vj[0]) * vw;
        accR[1] += (uy - vj[1]) * vw;
        accR[2] += (uz - vj[2]) * vw;
      }
    } else {
      const int sg   = (w - 2)*8 + (lane & 7);
      const int jsub = lane >> 3;
      #pragma unroll
      for (int jj = 0; jj < 4; ++jj){
        const int j = jj*8 + jsub;
        const float aj = attL[j];
        const bf16x8 v = *(const bf16x8*)&bufij[j*LSTRIDE + sg*8];
        #pragma unroll
        for (int e = 0; e < 8; ++e) accR[e] += aj * (float)v[e];
      }
    }
  }

  // ---------- fused tail: reductions + node MLP + clamped writes -----------
  float* sF = (float*)bufm;   // [0..127]=h, [128..255]=magg, [256..511]=p, [512..639]=t1
  if (t < Hd) sF[t] = h[(size_t)node*Hd + t];

  if (w == 0 || w == 1){
    float v0 = accR[0], v1 = accR[1], v2 = accR[2];
    #pragma unroll
    for (int off = 1; off < 64; off <<= 1){
      v0 += __shfl_xor(v0, off, 64);
      v1 += __shfl_xor(v1, off, 64);
      v2 += __shfl_xor(v2, off, 64);
    }
    if (lane == 0){
      const float inv = 1.f / 511.f;
      if (w == 0){
        float o0 = pi[0] + v0*inv, o1 = pi[1] + v1*inv, o2 = pi[2] + v2*inv;
        out[2*Nn*Hd + node*3 + 0] = fminf(fmaxf(o0, -100.f), 100.f);
        out[2*Nn*Hd + node*3 + 1] = fminf(fmaxf(o1, -100.f), 100.f);
        out[2*Nn*Hd + node*3 + 2] = fminf(fmaxf(o2, -100.f), 100.f);
      } else {
        float o0 = vi[0] + v0*inv, o1 = vi[1] + v1*inv, o2 = vi[2] + v2*inv;
        out[2*Nn*Hd + 2*Nn*3 + node*3 + 0] = fminf(fmaxf(o0, -100.f), 100.f);
        out[2*Nn*Hd + 2*Nn*3 + node*3 + 1] = fminf(fmaxf(o1, -100.f), 100.f);
        out[2*Nn*Hd + 2*Nn*3 + node*3 + 2] = fminf(fmaxf(o2, -100.f), 100.f);
      }
    }
  } else {
    const int sg = (w - 2)*8 + (lane & 7);
    #pragma unroll
    for (int off = 8; off < 64; off <<= 1){
      #pragma unroll
      for (int e = 0; e < 8; ++e) accR[e] += __shfl_xor(accR[e], off, 64);
    }
    if ((lane >> 3) == 0){
      *(float4*)&sF[128 + sg*8 + 0] = make_float4(accR[0], accR[1], accR[2], accR[3]);
      *(float4*)&sF[128 + sg*8 + 4] = make_float4(accR[4], accR[5], accR[6], accR[7]);
    }
  }
  __syncthreads();

  // node MLP layer 1 (split-c over 2 halves)
  {
    const int k = t & 127, ch = t >> 7;
    const int cb = ch*Hd;
    float a0=0.f,a1=0.f,a2=0.f,a3=0.f;
    #pragma unroll 8
    for (int cc = 0; cc < Hd; cc += 4){
      a0 += sF[cb+cc+0] * Wn1[(cb+cc+0)*Hd + k];
      a1 += sF[cb+cc+1] * Wn1[(cb+cc+1)*Hd + k];
      a2 += sF[cb+cc+2] * Wn1[(cb+cc+2)*Hd + k];
      a3 += sF[cb+cc+3] * Wn1[(cb+cc+3)*Hd + k];
    }
    sF[256 + ch*128 + k] = (a0+a1)+(a2+a3);
  }
  __syncthreads();
  if (t < Hd) sF[512 + t] = fsilu(sF[256 + t] + sF[384 + t] + bn1[t]);
  __syncthreads();
  {
    const int k = t & 127, ch = t >> 7;
    const int cb = ch*64;
    float a0=0.f,a1=0.f,a2=0.f,a3=0.f;
    #pragma unroll 8
    for (int cc = 0; cc < 64; cc += 4){
      a0 += sF[512+cb+cc+0] * Wn2[(cb+cc+0)*Hd + k];
      a1 += sF[512+cb+cc+1] * Wn2[(cb+cc+1)*Hd + k];
      a2 += sF[512+cb+cc+2] * Wn2[(cb+cc+2)*Hd + k];
      a3 += sF[512+cb+cc+3] * Wn2[(cb+cc+3)*Hd + k];
    }
    sF[256 + ch*128 + k] = (a0+a1)+(a2+a3);
  }
  __syncthreads();
  if (t < Hd)
    out[(size_t)node*Hd + t] = sF[t] + sF[256 + t] + sF[384 + t] + bn2[t];
}

// ===========================================================================
// Fallback trio (R9, unchanged): used if co-residency < 4 blocks/CU
// ===========================================================================
__global__ __launch_bounds__(256) void prep(const float* __restrict__ h,
                                            const float* __restrict__ We1,
                                            const float* __restrict__ be1,
                                            const float* __restrict__ We2,
                                            const float* __restrict__ Wp1,
                                            const float* __restrict__ Wv1,
                                            float* __restrict__ A,
                                            float* __restrict__ Bm,
                                            __bf16* __restrict__ dst,
                                            float* __restrict__ zbase){
  if (blockIdx.x < 256){
    const int r0 = blockIdx.x * 4;
    const int k = threadIdx.x & 127, ch = threadIdx.x >> 7;
    __shared__ float hL[4][Hd];
    __shared__ float pa[2][4][Hd], pb[2][4][Hd];
    for (int idx = threadIdx.x; idx < 4*Hd; idx += 256)
      hL[idx >> 7][idx & 127] = h[r0*Hd + idx];
    __syncthreads();
    float a[4] = {0.f,0.f,0.f,0.f}, bb[4] = {0.f,0.f,0.f,0.f};
    const int cbase = ch*64;
    #pragma unroll 4
    for (int cc = 0; cc < 64; ++cc){
      const int c = cbase + cc;
      const float wa = We1[c*Hd + k];
      const float wb = We1[(c + Hd)*Hd + k];
      #pragma unroll
      for (int rr = 0; rr < 4; ++rr){
        a[rr]  += hL[rr][c] * wa;
        bb[rr] += hL[rr][c] * wb;
      }
    }
    #pragma unroll
    for (int rr = 0; rr < 4; ++rr){ pa[ch][rr][k] = a[rr]; pb[ch][rr][k] = bb[rr]; }
    __syncthreads();
    if (threadIdx.x < Hd){
      const float be = be1[k];
      #pragma unroll
      for (int rr = 0; rr < 4; ++rr){
        A[(r0+rr)*Hd + k]  = pa[0][rr][k] + pa[1][rr][k] + be;
        Bm[(r0+rr)*Hd + k] = pb[0][rr][k] + pb[1][rr][k];
      }
    }
  } else if (blockIdx.x < 280){
    const int blk = blockIdx.x - 256;
    const int which = blk >> 3, m = blk & 7;
    const float* src = (which == 0) ? We2 : (which == 1 ? Wp1 : Wv1);
    __bf16* d = dst + which * (Hd*Hd);
    #pragma unroll
    for (int it = 0; it < 8; ++it){
      const int sidx = m*2048 + it*256 + threadIdx.x;
      const int kk = sidx >> 7, cc = sidx & 127;
      const int s = kk >> 5, j = kk & 7;
      const int lane = ((kk >> 3) & 3)*16 + (cc & 15);
      const int n = cc >> 4;
      d[n*2048 + s*512 + lane*8 + j] = (__bf16)src[sidx];
    }
  } else {
    const int t0 = (blockIdx.x - 280)*256 + threadIdx.x;
    for (int idx = t0; idx < 137216; idx += 2048) zbase[idx] = 0.f;
  }
}

__global__ __launch_bounds__(256) void egnn_main(
    const float* __restrict__ pos, const float* __restrict__ vel,
    const float* __restrict__ We1, const float* __restrict__ be2,
    const float* __restrict__ Wa,  const float* __restrict__ ba,
    const float* __restrict__ bp1, const float* __restrict__ Wp2,
    const float* __restrict__ bv1, const float* __restrict__ Wv2,
    const float* __restrict__ A,   const float* __restrict__ Bm,
    const __bf16* __restrict__ Wsw,
    float* __restrict__ magg, float* __restrict__ posu, float* __restrict__ velu){

  const int t    = threadIdx.x;
  const int w    = t >> 6;
  const int lane = t & 63;
  const int q    = lane >> 4;
  const int l15  = lane & 15;
  const int node = blockIdx.x >> 1;
  const int half = blockIdx.x & 1;
  const int b    = node >> 9;

  __shared__ float AiL[Hd], wpL[Hd], wvL[Hd];
  __shared__ float be2L[Hd], bp1L[Hd], bv1L[Hd], WaL[Hd], Wp2L[Hd], Wv2L[Hd];
  __shared__ __align__(16) __bf16 bufm [TJ*LSTRIDE];
  __shared__ __align__(16) __bf16 bufij[TJ*LSTRIDE];
  __shared__ float partAtt[4][TJ], partP[4][TJ], partV[4][TJ];
  __shared__ float attL[TJ];

  if (t < Hd){
    AiL[t]  = A[node*Hd + t];
    wpL[t]  = We1[256*Hd + t];
    wvL[t]  = We1[257*Hd + t];
    be2L[t] = be2[t]; bp1L[t] = bp1[t]; bv1L[t] = bv1[t];
    WaL[t]  = Wa[t];  Wp2L[t] = Wp2[t]; Wv2L[t] = Wv2[t];
  }
  const float baV = ba[0];
  const float* pi = &pos[(size_t)node*3];
  const float* vi = &vel[(size_t)node*3];
  const float px = rfl(pi[0]), py = rfl(pi[1]), pz = rfl(pi[2]);
  const float ux = rfl(vi[0]), uy = rfl(vi[1]), uz = rfl(vi[2]);
  __syncthreads();

  const bf16x8* We2s = (const bf16x8*)(Wsw);
  const bf16x8* Wp1s = (const bf16x8*)(Wsw + Hd*Hd);
  const bf16x8* Wv1s = (const bf16x8*)(Wsw + 2*Hd*Hd);

  float accR[8];
  #pragma unroll
  for (int e = 0; e < 8; ++e) accR[e] = 0.f;

  for (int jt = 0; jt < (Nn/2)/TJ; ++jt){
    const int j0 = half*(Nn/2) + jt * TJ;
    {
      const int g  = t & 15;
      const int j2 = t >> 4;
      const floatx4 a0 = *(const floatx4*)&AiL[g*8];
      const floatx4 a1 = *(const floatx4*)&AiL[g*8 + 4];
      const floatx4 p0 = *(const floatx4*)&wpL[g*8];
      const floatx4 p1 = *(const floatx4*)&wpL[g*8 + 4];
      const floatx4 v0 = *(const floatx4*)&wvL[g*8];
      const floatx4 v1 = *(const floatx4*)&wvL[g*8 + 4];
      #pragma unroll
      for (int rr = 0; rr < 2; ++rr){
        const int j = j2 + rr*16;
        const int jg = j0 + j;
        const float* pj = &pos[(size_t)(b*Nn + jg)*3];
        const float* vj = &vel[(size_t)(b*Nn + jg)*3];
        const float dx = px - pj[0], dy = py - pj[1], dz = pz - pj[2];
        const float dp = dx*dx + dy*dy + dz*dz;
        const float ex = ux - vj[0], ey = uy - vj[1], ez = uz - vj[2];
        const float dv = ex*ex + ey*ey + ez*ez;
        const floatx4* Bp4 = (const floatx4*)&Bm[((size_t)(b*Nn + jg))*Hd + g*8];
        const floatx4 b0 = Bp4[0], b1 = Bp4[1];
        union { bf16x8 v; __hip_bfloat162 h2[4]; } o;
        float x[8];
        #pragma unroll
        for (int e = 0; e < 4; ++e){
          x[e]   = fsilu(a0[e] + b0[e] + dp*p0[e] + dv*v0[e]);
          x[4+e] = fsilu(a1[e] + b1[e] + dp*p1[e] + dv*v1[e]);
        }
        o.h2[0] = __float22bfloat162_rn(make_float2(x[0], x[1]));
        o.h2[1] = __float22bfloat162_rn(make_float2(x[2], x[3]));
        o.h2[2] = __float22bfloat162_rn(make_float2(x[4], x[5]));
        o.h2[3] = __float22bfloat162_rn(make_float2(x[6], x[7]));
        *(bf16x8*)&bufm[j*LSTRIDE + g*8] = o.v;
      }
    }
    __syncthreads();
    {
      floatx4 acc[2][2];
      gemm_kloopT(bufm, We2s, w, lane, q, l15, acc);
      const int fb0 = 32*w + 4*q, fb1 = fb0 + 16;
      const floatx4 be0 = *(const floatx4*)&be2L[fb0];
      const floatx4 be1v = *(const floatx4*)&be2L[fb1];
      const floatx4 wa0 = *(const floatx4*)&WaL[fb0];
      const floatx4 wa1 = *(const floatx4*)&WaL[fb1];
      float aw[2];
      #pragma unroll
      for (int n = 0; n < 2; ++n){
        const int j = 16*n + l15;
        float s0[4], s1[4];
        #pragma unroll
        for (int r = 0; r < 4; ++r){
          s0[r] = fsilu(acc[0][n][r] + be0[r]);
          s1[r] = fsilu(acc[1][n][r] + be1v[r]);
        }
        aw[n] = s0[0]*wa0[0] + s0[1]*wa0[1] + s0[2]*wa0[2] + s0[3]*wa0[3]
              + s1[0]*wa1[0] + s1[1]*wa1[1] + s1[2]*wa1[2] + s1[3]*wa1[3];
        union { bf16x4 v; __hip_bfloat162 h2[2]; } p0k, p1k;
        p0k.h2[0] = __float22bfloat162_rn(make_float2(s0[0], s0[1]));
        p0k.h2[1] = __float22bfloat162_rn(make_float2(s0[2], s0[3]));
        p1k.h2[0] = __float22bfloat162_rn(make_float2(s1[0], s1[1]));
        p1k.h2[1] = __float22bfloat162_rn(make_float2(s1[2], s1[3]));
        *(bf16x4*)&bufij[j*LSTRIDE + fb0] = p0k.v;
        *(bf16x4*)&bufij[j*LSTRIDE + fb1] = p1k.v;
      }
      aw[0] += __shfl_xor(aw[0], 16, 64); aw[0] += __shfl_xor(aw[0], 32, 64);
      aw[1] += __shfl_xor(aw[1], 16, 64); aw[1] += __shfl_xor(aw[1], 32, 64);
      if (lane < 16){
        partAtt[w][l15]      = aw[0];
        partAtt[w][16 + l15] = aw[1];
      }
    }
    __syncthreads();
    {
      const float att0 = fsigm(partAtt[0][l15] + partAtt[1][l15] +
                               partAtt[2][l15] + partAtt[3][l15] + baV);
      const float att1 = fsigm(partAtt[0][16+l15] + partAtt[1][16+l15] +
                               partAtt[2][16+l15] + partAtt[3][16+l15] + baV);
      if (w == 0 && lane < 16){ attL[l15] = att0; attL[16 + l15] = att1; }
      floatx4 acc[2][2];
      gemm_kloopT(bufij, Wp1s, w, lane, q, l15, acc);
      wdotT(acc, att0, att1, bp1L, Wp2L, w, lane, q, l15, partP);
      gemm_kloopT(bufij, Wv1s, w, lane, q, l15, acc);
      wdotT(acc, att0, att1, bv1L, Wv2L, w, lane, q, l15, partV);
    }
    __syncthreads();
    if (w == 0){
      if (lane < TJ){
        const int jg = j0 + lane;
        const float* pj = &pos[(size_t)(b*Nn + jg)*3];
        const float s4 = partP[0][lane] + partP[1][lane] + partP[2][lane] + partP[3][lane];
        const float pw = ftanh(s4);
        accR[0] += (px - pj[0]) * pw;
        accR[1] += (py - pj[1]) * pw;
        accR[2] += (pz - pj[2]) * pw;
      }
    } else if (w == 1){
      if (lane < TJ){
        const int jg = j0 + lane;
        const float* vj = &vel[(size_t)(b*Nn + jg)*3];
        const float s4 = partV[0][lane] + partV[1][lane] + partV[2][lane] + partV[3][lane];
        const float vw = ftanh(s4);
        accR[0] += (ux - vj[0]) * vw;
        accR[1] += (uy - vj[1]) * vw;
        accR[2] += (uz - vj[2]) * vw;
      }
    } else {
      const int sg   = (w - 2)*8 + (lane & 7);
      const int jsub = lane >> 3;
      #pragma unroll
      for (int jj = 0; jj < 4; ++jj){
        const int j = jj*8 + jsub;
        const float aj = attL[j];
        const bf16x8 v = *(const bf16x8*)&bufij[j*LSTRIDE + sg*8];
        #pragma unroll
        for (int e = 0; e < 8; ++e) accR[e] += aj * (float)v[e];
      }
    }
  }

  if (w == 0 || w == 1){
    float v0 = accR[0], v1 = accR[1], v2 = accR[2];
    #pragma unroll
    for (int off = 1; off < 64; off <<= 1){
      v0 += __shfl_xor(v0, off, 64);
      v1 += __shfl_xor(v1, off, 64);
      v2 += __shfl_xor(v2, off, 64);
    }
    if (lane == 0){
      float* dst = (w == 0) ? &posu[node*3] : &velu[node*3];
      atomicAdd(&dst[0], v0);
      atomicAdd(&dst[1], v1);
      atomicAdd(&dst[2], v2);
    }
  } else {
    const int sg = (w - 2)*8 + (lane & 7);
    #pragma unroll
    for (int off = 8; off < 64; off <<= 1){
      #pragma unroll
      for (int e = 0; e < 8; ++e) accR[e] += __shfl_xor(accR[e], off, 64);
    }
    if ((lane >> 3) == 0){
      #pragma unroll
      for (int e = 0; e < 8; ++e)
        atomicAdd(&magg[node*Hd + sg*8 + e], accR[e]);
    }
  }
}

__global__ __launch_bounds__(256) void egnn_final(
    const float* __restrict__ h, const float* __restrict__ pos, const float* __restrict__ vel,
    const float* __restrict__ Wn1, const float* __restrict__ bn1,
    const float* __restrict__ Wn2, const float* __restrict__ bn2,
    const float* __restrict__ magg, const float* __restrict__ posu,
    const float* __restrict__ velu, float* __restrict__ out){
  const int row = blockIdx.x;
  const int t = threadIdx.x;
  const int k = t & 127, ch = t >> 7;
  __shared__ float ni[2*Hd];
  __shared__ float p1[2][Hd], t1[Hd];
  ni[t] = (t < Hd) ? h[row*Hd + t] : magg[row*Hd + (t - Hd)];
  __syncthreads();
  {
    float a0=0.f,a1=0.f,a2=0.f,a3=0.f;
    const int cb = ch*Hd;
    #pragma unroll 8
    for (int cc = 0; cc < Hd; cc += 4){
      a0 += ni[cb+cc+0] * Wn1[(cb+cc+0)*Hd + k];
      a1 += ni[cb+cc+1] * Wn1[(cb+cc+1)*Hd + k];
      a2 += ni[cb+cc+2] * Wn1[(cb+cc+2)*Hd + k];
      a3 += ni[cb+cc+3] * Wn1[(cb+cc+3)*Hd + k];
    }
    p1[ch][k] = (a0+a1)+(a2+a3);
  }
  __syncthreads();
  if (t < Hd) t1[t] = fsilu(p1[0][t] + p1[1][t] + bn1[t]);
  __syncthreads();
  {
    float a0=0.f,a1=0.f,a2=0.f,a3=0.f;
    const int cb = ch*64;
    #pragma unroll 8
    for (int cc = 0; cc < 64; cc += 4){
      a0 += t1[cb+cc+0] * Wn2[(cb+cc+0)*Hd + k];
      a1 += t1[cb+cc+1] * Wn2[(cb+cc+1)*Hd + k];
      a2 += t1[cb+cc+2] * Wn2[(cb+cc+2)*Hd + k];
      a3 += t1[cb+cc+3] * Wn2[(cb+cc+3)*Hd + k];
    }
    p1[ch][k] = (a0+a1)+(a2+a3);
  }
  __syncthreads();
  if (t < Hd){
    out[row*Hd + t] = ni[t] + p1[0][t] + p1[1][t] + bn2[t];
  } else if (t < Hd + 3){
    const int d = t - Hd;
    const float v = pos[row*3 + d] + posu[row*3 + d] * (1.f/511.f);
    out[2*Nn*Hd + row*3 + d] = fminf(fmaxf(v, -100.f), 100.f);
  } else if (t < Hd + 6){
    const int d = t - Hd - 3;
    const float v = vel[row*3 + d] + velu[row*3 + d] * (1.f/511.f);
    out[2*Nn*Hd + 2*Nn*3 + row*3 + d] = fminf(fmaxf(v, -100.f), 100.f);
  }
}

// ---------------------------------------------------------------------------
extern "C" void kernel_launch(void* const* d_in, const int* in_sizes, int n_in,
                              void* d_out, int out_size, void* d_ws, size_t ws_size,
                              hipStream_t stream){
  const float* h   = (const float*)d_in[0];
  const float* pos = (const float*)d_in[1];
  const float* vel = (const float*)d_in[2];
  const float* We1 = (const float*)d_in[3];
  const float* be1 = (const float*)d_in[4];
  const float* We2 = (const float*)d_in[5];
  const float* be2 = (const float*)d_in[6];
  const float* Wa  = (const float*)d_in[7];
  const float* ba  = (const float*)d_in[8];
  const float* Wp1 = (const float*)d_in[9];
  const float* bp1 = (const float*)d_in[10];
  const float* Wp2 = (const float*)d_in[11];
  const float* Wv1 = (const float*)d_in[12];
  const float* bv1 = (const float*)d_in[13];
  const float* Wv2 = (const float*)d_in[14];
  const float* Wn1 = (const float*)d_in[15];
  const float* bn1 = (const float*)d_in[16];
  const float* Wn2 = (const float*)d_in[17];
  const float* bn2 = (const float*)d_in[18];

  float* ws = (float*)d_ws;
  float*  A    = ws;                     // 1024*128 floats (fallback only)
  float*  Bmm  = ws + 131072;            // 1024*128
  float*  magg = ws + 262144;            // fallback only
  float*  posu = ws + 393216;            // fallback only
  float*  velu = ws + 396288;            // fallback only
  __bf16* Wsw  = (__bf16*)(ws + 399360); // 3*16384 bf16
  float*  outp = (float*)d_out;

  int maxB = 0;
  hipError_t qe = hipOccupancyMaxActiveBlocksPerMultiprocessor(
      &maxB, (const void*)egnn_coop, 256, 0);
  const bool coop = (qe == hipSuccess && maxB >= 4);   // need 1024 co-resident

  if (coop){
    void* args[] = {
      (void*)&h, (void*)&pos, (void*)&vel, (void*)&We1, (void*)&be1,
      (void*)&be2, (void*)&Wa, (void*)&ba, (void*)&bp1, (void*)&Wp2,
      (void*)&bv1, (void*)&Wv2, (void*)&Wn1, (void*)&bn1, (void*)&Wn2,
      (void*)&bn2, (void*)&We2, (void*)&Wp1, (void*)&Wv1,
      (void*)&Bmm, (void*)&Wsw, (void*)&outp
    };
    hipLaunchCooperativeKernel((const void*)egnn_coop, dim3(1024), dim3(256),
                               args, 0, stream);
  } else {
    prep      <<<dim3(288),  dim3(256), 0, stream>>>(h, We1, be1, We2, Wp1, Wv1,
                                                     A, Bmm, Wsw, magg);
    egnn_main <<<dim3(2048), dim3(256), 0, stream>>>(pos, vel, We1, be2, Wa, ba, bp1, Wp2,
                                                     bv1, Wv2, A, Bmm, Wsw, magg, posu, velu);
    egnn_final<<<dim3(1024), dim3(256), 0, stream>>>(h, pos, vel, Wn1, bn1, Wn2, bn2,
                                                     magg, posu, velu, outp);
  }
}